// Round 1
// baseline (1668.255 us; speedup 1.0000x reference)
//
#include <hip/hip_runtime.h>

#define TPB 256
#define HID 128
#define IN_C 4
#define POOL_NODES 64

// ---------------------------------------------------------------------------
// K0: init deg (=1.0 self-loop), zero out, zero cnt
__global__ void k_init(float* deg, float* out, int* cnt, int n, int outsz, int bg) {
    int i = blockIdx.x * blockDim.x + threadIdx.x;
    if (i < n) deg[i] = 1.0f;
    if (i < outsz) out[i] = 0.0f;
    if (i < bg) cnt[i] = 0;
}

// K1: deg[dst] += 1 per edge; cnt[batch] += 1 per node (e >= n so one grid covers both)
__global__ void k_deg_cnt(const int* __restrict__ dst, float* deg,
                          const int* __restrict__ batch, int* cnt, int e, int n) {
    int i = blockIdx.x * blockDim.x + threadIdx.x;
    if (i < e) atomicAdd(&deg[dst[i]], 1.0f);
    if (i < n) atomicAdd(&cnt[batch[i]], 1);
}

// K2: dinv = rsqrt(deg), in place (deg >= 1 always, self-loop)
__global__ void k_rsqrt(float* deg, int n) {
    int i = blockIdx.x * blockDim.x + threadIdx.x;
    if (i < n) deg[i] = rsqrtf(deg[i]);
}

// K3: per-edge norm = dinv[src]*dinv[dst]
__global__ void k_norm(const int* __restrict__ src, const int* __restrict__ dst,
                       const float* __restrict__ dinv, float* normv, int e) {
    int i = blockIdx.x * blockDim.x + threadIdx.x;
    if (i < e) normv[i] = dinv[src[i]] * dinv[dst[i]];
}

// K4: xprop init with self-loop term: xp[v][k] = dinv[v]^2 * x[v][k]   (4 channels)
__global__ void k_xprop(const float* __restrict__ x, const float* __restrict__ dinv,
                        float* xp, int n) {
    int i = blockIdx.x * blockDim.x + threadIdx.x;
    if (i < n * IN_C) {
        int v = i >> 2;
        float dv = dinv[v];
        xp[i] = dv * dv * x[i];
    }
}

// K5: scatter layer-1 propagation on raw 4-channel x (32x cheaper than post-W1)
__global__ void k_scatter1(const int* __restrict__ src, const int* __restrict__ dst,
                           const float* __restrict__ normv, const float* __restrict__ x,
                           float* xp, int e) {
    int i = blockIdx.x * blockDim.x + threadIdx.x;
    if (i >= e * IN_C) return;
    int eid = i >> 2, k = i & 3;
    int s = src[eid], d = dst[eid];
    atomicAdd(&xp[d * IN_C + k], normv[eid] * x[s * IN_C + k]);
}

// K6: f1 = relu(xp @ W1 + b1); acc2 init = dinv^2 * f1 (layer-2 self-loop term)
__global__ void k_f1(const float* __restrict__ xp, const float* __restrict__ W1,
                     const float* __restrict__ b1, const float* __restrict__ dinv,
                     float* f1, float* acc2, int n) {
    int i = blockIdx.x * blockDim.x + threadIdx.x;
    if (i >= n * HID) return;
    int v = i >> 7, c = i & (HID - 1);
    const float* xr = xp + v * IN_C;
    float s = xr[0] * W1[c] + xr[1] * W1[HID + c] + xr[2] * W1[2 * HID + c]
            + xr[3] * W1[3 * HID + c] + b1[c];
    float f = s > 0.0f ? s : 0.0f;
    f1[i] = f;
    float dv = dinv[v];
    acc2[i] = dv * dv * f;
}

// K7: the big one — layer-2 propagation scatter, 128 ch/edge
__global__ void k_scatter2(const int* __restrict__ src, const int* __restrict__ dst,
                           const float* __restrict__ normv, const float* __restrict__ f1,
                           float* acc2, int e) {
    int i = blockIdx.x * blockDim.x + threadIdx.x;
    if (i >= e * HID) return;   // 204.8M < 2^31
    int eid = i >> 7, c = i & (HID - 1);
    int s = src[eid], d = dst[eid];
    atomicAdd(&acc2[d * HID + c], normv[eid] * f1[s * HID + c]);
}

// K8: fused f2 = relu(acc2 @ W2 + b2) + segment-sum pool (batch is sorted).
// Each thread owns one W2 column in registers; acc2 rows are wave-uniform loads.
__global__ __launch_bounds__(HID) void k_mm2_pool(
        const float* __restrict__ acc2, const float* __restrict__ W2,
        const float* __restrict__ b2, const int* __restrict__ batch,
        float* out, int n) {
    int c = threadIdx.x;                 // 0..127
    int v0 = blockIdx.x * POOL_NODES;
    if (v0 >= n) return;

    float wcol[HID];
#pragma unroll
    for (int k = 0; k < HID; k++) wcol[k] = W2[k * HID + c];
    float bc = b2[c];

    int vend = v0 + POOL_NODES;
    if (vend > n) vend = n;

    float sum = 0.0f;
    int cur = batch[v0];
    for (int v = v0; v < vend; v++) {
        const float* arow = acc2 + (long)v * HID;
        float s = bc;
#pragma unroll
        for (int k = 0; k < HID; k++) s = fmaf(arow[k], wcol[k], s);
        s = s > 0.0f ? s : 0.0f;
        int b = batch[v];                // wave-uniform
        if (b != cur) {                  // uniform branch
            atomicAdd(&out[cur * HID + c], sum);
            sum = 0.0f;
            cur = b;
        }
        sum += s;
    }
    atomicAdd(&out[cur * HID + c], sum);
}

// K9: out[b][c] /= max(cnt[b], 1)
__global__ void k_div(float* out, const int* __restrict__ cnt, int outsz) {
    int i = blockIdx.x * blockDim.x + threadIdx.x;
    if (i < outsz) {
        int b = i >> 7;
        float cf = (float)cnt[b];
        out[i] = out[i] / fmaxf(cf, 1.0f);
    }
}

extern "C" void kernel_launch(void* const* d_in, const int* in_sizes, int n_in,
                              void* d_out, int out_size, void* d_ws, size_t ws_size,
                              hipStream_t stream) {
    const float* x   = (const float*)d_in[0];
    const int* ei    = (const int*)d_in[1];   // [2, E] flat: src then dst
    const int* batch = (const int*)d_in[2];
    const float* W1  = (const float*)d_in[3];
    const float* b1  = (const float*)d_in[4];
    const float* W2  = (const float*)d_in[5];
    const float* b2  = (const float*)d_in[6];
    float* out = (float*)d_out;

    int n  = in_sizes[0] / IN_C;
    int e  = in_sizes[1] / 2;
    int bg = out_size / HID;
    const int* src = ei;
    const int* dst = ei + e;

    // carve workspace (total ~111 MB)
    size_t off = 0;
    char* base = (char*)d_ws;
    auto carve = [&](size_t bytes) -> void* {
        void* p = base + off;
        off += (bytes + 255) & ~(size_t)255;
        return p;
    };
    float* dinv  = (float*)carve((size_t)n * 4);
    float* normv = (float*)carve((size_t)e * 4);
    float* xp    = (float*)carve((size_t)n * IN_C * 4);
    float* f1    = (float*)carve((size_t)n * HID * 4);
    float* acc2  = (float*)carve((size_t)n * HID * 4);
    int*   cnt   = (int*)carve((size_t)bg * 4);
    (void)ws_size;

    int gN = (n + TPB - 1) / TPB;
    int gE = (e + TPB - 1) / TPB;

    k_init<<<gN, TPB, 0, stream>>>(dinv, out, cnt, n, out_size, bg);
    k_deg_cnt<<<gE, TPB, 0, stream>>>(dst, dinv, batch, cnt, e, n);
    k_rsqrt<<<gN, TPB, 0, stream>>>(dinv, n);
    k_norm<<<gE, TPB, 0, stream>>>(src, dst, dinv, normv, e);
    k_xprop<<<(n * IN_C + TPB - 1) / TPB, TPB, 0, stream>>>(x, dinv, xp, n);
    k_scatter1<<<(e * IN_C + TPB - 1) / TPB, TPB, 0, stream>>>(src, dst, normv, x, xp, e);
    k_f1<<<(n * HID + TPB - 1) / TPB, TPB, 0, stream>>>(xp, W1, b1, dinv, f1, acc2, n);
    long tot2 = (long)e * HID;
    k_scatter2<<<(int)((tot2 + TPB - 1) / TPB), TPB, 0, stream>>>(src, dst, normv, f1, acc2, e);
    k_mm2_pool<<<(n + POOL_NODES - 1) / POOL_NODES, HID, 0, stream>>>(acc2, W2, b2, batch, out, n);
    k_div<<<(out_size + TPB - 1) / TPB, TPB, 0, stream>>>(out, cnt, out_size);
}

// Round 2
// 924.106 us; speedup vs baseline: 1.8053x; 1.8053x over previous
//
#include <hip/hip_runtime.h>

#define TPB 256
#define HID 128
#define IN_C 4
#define POOL_NODES 64
#define SCAN_T 1024

// ---------------------------------------------------------------------------
// K0: zero deg_i and out
__global__ void k_init(int* deg_i, float* out, int n, int outsz) {
    int i = blockIdx.x * blockDim.x + threadIdx.x;
    if (i < n) deg_i[i] = 0;
    if (i < outsz) out[i] = 0.0f;
}

// K1: in-degree histogram (int atomics, random dsts -> low contention)
__global__ void k_hist(const int* __restrict__ dst, int* deg_i, int e) {
    int i = blockIdx.x * blockDim.x + threadIdx.x;
    if (i < e) atomicAdd(&deg_i[dst[i]], 1);
}

// K2: per-graph node counts via binary search on sorted batch (no atomics)
__global__ void k_cnt(const int* __restrict__ batch, int* cnt, int n, int bg) {
    int b = blockIdx.x * blockDim.x + threadIdx.x;
    if (b >= bg) return;
    int lo0 = 0, hi0 = n;
    while (lo0 < hi0) { int m = (lo0 + hi0) >> 1; if (batch[m] < b) lo0 = m + 1; else hi0 = m; }
    int lo1 = lo0, hi1 = n;
    while (lo1 < hi1) { int m = (lo1 + hi1) >> 1; if (batch[m] < b + 1) lo1 = m + 1; else hi1 = m; }
    cnt[b] = lo1 - lo0;
}

// K3: single-block exclusive scan of deg_i -> off, cursor (copy), off[n]=e
__global__ __launch_bounds__(SCAN_T) void k_scan(const int* __restrict__ deg_i,
                                                 int* off, int* cursor, int n, int e) {
    __shared__ int sums[SCAN_T];
    int t = threadIdx.x;
    int per = (n + SCAN_T - 1) / SCAN_T;
    int lo = t * per, hi = lo + per; if (hi > n) hi = n; if (lo > n) lo = n;
    int s = 0;
    for (int i = lo; i < hi; i++) s += deg_i[i];
    sums[t] = s;
    __syncthreads();
    for (int d = 1; d < SCAN_T; d <<= 1) {
        int v = 0;
        if (t >= d) v = sums[t - d];
        __syncthreads();
        if (t >= d) sums[t] += v;
        __syncthreads();
    }
    int run = sums[t] - s;          // exclusive prefix for this chunk
    for (int i = lo; i < hi; i++) {
        off[i] = run; cursor[i] = run;
        run += deg_i[i];
    }
    if (t == 0) off[n] = e;
}

// K4: dinv = rsqrt(in_deg + 1 self-loop)
__global__ void k_dinv(const int* __restrict__ deg_i, float* dinv, int n) {
    int i = blockIdx.x * blockDim.x + threadIdx.x;
    if (i < n) dinv[i] = rsqrtf((float)deg_i[i] + 1.0f);
}

// K5: counting-sort fill: src_sorted grouped by dst
__global__ void k_fillpos(const int* __restrict__ src, const int* __restrict__ dst,
                          int* cursor, int* src_sorted, int e) {
    int i = blockIdx.x * blockDim.x + threadIdx.x;
    if (i >= e) return;
    int d = dst[i];
    int p = atomicAdd(&cursor[d], 1);
    src_sorted[p] = src[i];
}

// K6: layer-1 propagation as gather on raw 4-channel x (one thread per node)
__global__ void k_gather1(const int* __restrict__ off, const int* __restrict__ src_sorted,
                          const float* __restrict__ dinv, const float* __restrict__ x,
                          float* xp, int n) {
    int v = blockIdx.x * blockDim.x + threadIdx.x;
    if (v >= n) return;
    float dv = dinv[v];
    const float4* x4 = (const float4*)x;
    float4 xv = x4[v];
    float sl = dv * dv;              // self-loop norm
    float a0 = sl * xv.x, a1 = sl * xv.y, a2 = sl * xv.z, a3 = sl * xv.w;
    int e0 = off[v], e1 = off[v + 1];
    for (int e = e0; e < e1; e++) {
        int s = src_sorted[e];
        float nrm = dinv[s] * dv;
        float4 xs = x4[s];
        a0 = fmaf(nrm, xs.x, a0); a1 = fmaf(nrm, xs.y, a1);
        a2 = fmaf(nrm, xs.z, a2); a3 = fmaf(nrm, xs.w, a3);
    }
    float4* xp4 = (float4*)xp;
    xp4[v] = make_float4(a0, a1, a2, a3);
}

// K7: f1 = relu(xp @ W1 + b1)
__global__ void k_f1(const float* __restrict__ xp, const float* __restrict__ W1,
                     const float* __restrict__ b1, float* f1, int n) {
    int i = blockIdx.x * blockDim.x + threadIdx.x;
    if (i >= n * HID) return;
    int v = i >> 7, c = i & (HID - 1);
    const float4* xr = (const float4*)(xp + v * IN_C);
    float4 xv = *xr;
    float s = fmaf(xv.x, W1[c],
              fmaf(xv.y, W1[HID + c],
              fmaf(xv.z, W1[2 * HID + c],
              fmaf(xv.w, W1[3 * HID + c], b1[c]))));
    f1[i] = s > 0.0f ? s : 0.0f;
}

// K8: layer-2 propagation as gather: one 128-thread block per node.
// Each edge = one coalesced 512B read of the f1 source row; acc in registers;
// one streaming write of the acc2 row. Zero atomics.
__global__ __launch_bounds__(HID) void k_gather2(
        const int* __restrict__ off, const int* __restrict__ src_sorted,
        const float* __restrict__ dinv, const float* __restrict__ f1,
        float* acc2, int n) {
    int v = blockIdx.x;
    if (v >= n) return;
    int c = threadIdx.x;
    float dv = dinv[v];
    float acc = dv * dv * f1[(long)v * HID + c];   // self-loop term
    int e0 = off[v], e1 = off[v + 1];
    for (int e = e0; e < e1; e++) {
        int s = src_sorted[e];
        float nrm = dinv[s] * dv;
        acc = fmaf(nrm, f1[(long)s * HID + c], acc);
    }
    acc2[(long)v * HID + c] = acc;
}

// K9: fused f2 = relu(acc2 @ W2 + b2) + segment-sum pool (batch sorted).
__global__ __launch_bounds__(HID) void k_mm2_pool(
        const float* __restrict__ acc2, const float* __restrict__ W2,
        const float* __restrict__ b2, const int* __restrict__ batch,
        float* out, int n) {
    int c = threadIdx.x;                 // 0..127
    int v0 = blockIdx.x * POOL_NODES;
    if (v0 >= n) return;

    float wcol[HID];
#pragma unroll
    for (int k = 0; k < HID; k++) wcol[k] = W2[k * HID + c];
    float bc = b2[c];

    int vend = v0 + POOL_NODES;
    if (vend > n) vend = n;

    float sum = 0.0f;
    int cur = batch[v0];
    for (int v = v0; v < vend; v++) {
        const float* arow = acc2 + (long)v * HID;
        float s = bc;
#pragma unroll
        for (int k = 0; k < HID; k++) s = fmaf(arow[k], wcol[k], s);
        s = s > 0.0f ? s : 0.0f;
        int b = batch[v];                // wave-uniform
        if (b != cur) {
            atomicAdd(&out[cur * HID + c], sum);
            sum = 0.0f;
            cur = b;
        }
        sum += s;
    }
    atomicAdd(&out[cur * HID + c], sum);
}

// K10: out[b][c] /= max(cnt[b], 1)
__global__ void k_div(float* out, const int* __restrict__ cnt, int outsz) {
    int i = blockIdx.x * blockDim.x + threadIdx.x;
    if (i < outsz) {
        int b = i >> 7;
        float cf = (float)cnt[b];
        out[i] = out[i] / fmaxf(cf, 1.0f);
    }
}

extern "C" void kernel_launch(void* const* d_in, const int* in_sizes, int n_in,
                              void* d_out, int out_size, void* d_ws, size_t ws_size,
                              hipStream_t stream) {
    const float* x   = (const float*)d_in[0];
    const int* ei    = (const int*)d_in[1];   // [2, E] flat: src then dst
    const int* batch = (const int*)d_in[2];
    const float* W1  = (const float*)d_in[3];
    const float* b1  = (const float*)d_in[4];
    const float* W2  = (const float*)d_in[5];
    const float* b2  = (const float*)d_in[6];
    float* out = (float*)d_out;

    int n  = in_sizes[0] / IN_C;
    int e  = in_sizes[1] / 2;
    int bg = out_size / HID;
    const int* src = ei;
    const int* dst = ei + e;

    size_t off_b = 0;
    char* base = (char*)d_ws;
    auto carve = [&](size_t bytes) -> void* {
        void* p = base + off_b;
        off_b += (bytes + 255) & ~(size_t)255;
        return p;
    };
    int*   deg_i      = (int*)carve((size_t)n * 4);
    int*   off        = (int*)carve((size_t)(n + 1) * 4);
    int*   cursor     = (int*)carve((size_t)n * 4);
    int*   src_sorted = (int*)carve((size_t)e * 4);
    float* dinv       = (float*)carve((size_t)n * 4);
    float* xp         = (float*)carve((size_t)n * IN_C * 4);
    float* f1         = (float*)carve((size_t)n * HID * 4);
    float* acc2       = (float*)carve((size_t)n * HID * 4);
    int*   cnt        = (int*)carve((size_t)bg * 4);
    (void)ws_size;

    int gN = (n + TPB - 1) / TPB;
    int gE = (e + TPB - 1) / TPB;

    k_init<<<gN, TPB, 0, stream>>>(deg_i, out, n, out_size);
    k_hist<<<gE, TPB, 0, stream>>>(dst, deg_i, e);
    k_cnt<<<1, 64, 0, stream>>>(batch, cnt, n, bg);
    k_scan<<<1, SCAN_T, 0, stream>>>(deg_i, off, cursor, n, e);
    k_dinv<<<gN, TPB, 0, stream>>>(deg_i, dinv, n);
    k_fillpos<<<gE, TPB, 0, stream>>>(src, dst, cursor, src_sorted, e);
    k_gather1<<<gN, TPB, 0, stream>>>(off, src_sorted, dinv, x, xp, n);
    k_f1<<<(n * HID + TPB - 1) / TPB, TPB, 0, stream>>>(xp, W1, b1, f1, n);
    k_gather2<<<n, HID, 0, stream>>>(off, src_sorted, dinv, f1, acc2, n);
    k_mm2_pool<<<(n + POOL_NODES - 1) / POOL_NODES, HID, 0, stream>>>(acc2, W2, b2, batch, out, n);
    k_div<<<(out_size + TPB - 1) / TPB, TPB, 0, stream>>>(out, cnt, out_size);
}

// Round 3
// 706.052 us; speedup vs baseline: 2.3628x; 1.3088x over previous
//
#include <hip/hip_runtime.h>

#define TPB 256
#define HID 128
#define IN_C 4
#define POOL_NODES 64
#define SCAN_TPB 256
#define SCAN_CHUNK 1024   // 4 elements per thread

// ---------------------------------------------------------------------------
// K0: zero deg_i and out
__global__ void k_init(int* deg_i, float* out, int n, int outsz) {
    int i = blockIdx.x * blockDim.x + threadIdx.x;
    if (i < n) deg_i[i] = 0;
    if (i < outsz) out[i] = 0.0f;
}

// K1: in-degree histogram (int atomics, random dsts -> low contention)
__global__ void k_hist(const int* __restrict__ dst, int* deg_i, int e) {
    int i = blockIdx.x * blockDim.x + threadIdx.x;
    if (i < e) atomicAdd(&deg_i[dst[i]], 1);
}

// K2: per-graph node counts via binary search on sorted batch (no atomics)
__global__ void k_cnt(const int* __restrict__ batch, int* cnt, int n, int bg) {
    int b = blockIdx.x * blockDim.x + threadIdx.x;
    if (b >= bg) return;
    int lo0 = 0, hi0 = n;
    while (lo0 < hi0) { int m = (lo0 + hi0) >> 1; if (batch[m] < b) lo0 = m + 1; else hi0 = m; }
    int lo1 = lo0, hi1 = n;
    while (lo1 < hi1) { int m = (lo1 + hi1) >> 1; if (batch[m] < b + 1) lo1 = m + 1; else hi1 = m; }
    cnt[b] = lo1 - lo0;
}

// K3a: per-block sums of deg_i (block = SCAN_CHUNK elements)
__global__ __launch_bounds__(SCAN_TPB) void k_scan_part(const int* __restrict__ deg_i,
                                                        int* bsum, int n) {
    __shared__ int red[SCAN_TPB];
    int b = blockIdx.x, t = threadIdx.x;
    int base = b * SCAN_CHUNK + t * 4;
    int s = 0;
#pragma unroll
    for (int k = 0; k < 4; k++) {
        int i = base + k;
        if (i < n) s += deg_i[i];
    }
    red[t] = s;
    __syncthreads();
    for (int d = SCAN_TPB / 2; d > 0; d >>= 1) {
        if (t < d) red[t] += red[t + d];
        __syncthreads();
    }
    if (t == 0) bsum[b] = red[0];
}

// K3b: single-block exclusive scan of block sums (handles arbitrary nb via tiles)
__global__ __launch_bounds__(1024) void k_scan_bsum(int* bsum, int nb) {
    __shared__ int red[1024];
    int t = threadIdx.x;
    int carry = 0;
    for (int base = 0; base < nb; base += 1024) {
        int i = base + t;
        int v = (i < nb) ? bsum[i] : 0;
        red[t] = v;
        __syncthreads();
        for (int d = 1; d < 1024; d <<= 1) {
            int x = 0;
            if (t >= d) x = red[t - d];
            __syncthreads();
            if (t >= d) red[t] += x;
            __syncthreads();
        }
        int tot = red[1023];
        if (i < nb) bsum[i] = carry + red[t] - v;   // exclusive
        carry += tot;
        __syncthreads();
    }
}

// K3c: final scan pass: local exclusive scan + block offset -> off, cursor;
// fused dinv = rsqrt(deg+1)
__global__ __launch_bounds__(SCAN_TPB) void k_scan_final(
        const int* __restrict__ deg_i, const int* __restrict__ bsum,
        int* off, int* cursor, float* dinv, int n, int e) {
    __shared__ int red[SCAN_TPB];
    int b = blockIdx.x, t = threadIdx.x;
    int base = b * SCAN_CHUNK + t * 4;
    int v[4];
    int s = 0;
#pragma unroll
    for (int k = 0; k < 4; k++) {
        int i = base + k;
        v[k] = (i < n) ? deg_i[i] : 0;
        s += v[k];
    }
    red[t] = s;
    __syncthreads();
    for (int d = 1; d < SCAN_TPB; d <<= 1) {
        int x = 0;
        if (t >= d) x = red[t - d];
        __syncthreads();
        if (t >= d) red[t] += x;
        __syncthreads();
    }
    int run = bsum[b] + red[t] - s;   // exclusive prefix for this thread's 4
#pragma unroll
    for (int k = 0; k < 4; k++) {
        int i = base + k;
        if (i < n) {
            off[i] = run;
            cursor[i] = run;
            dinv[i] = rsqrtf((float)v[k] + 1.0f);
            run += v[k];
        }
    }
    if (b == 0 && t == 0) off[n] = e;
}

// K5: counting-sort fill: src_sorted grouped by dst
__global__ void k_fillpos(const int* __restrict__ src, const int* __restrict__ dst,
                          int* cursor, int* src_sorted, int e) {
    int i = blockIdx.x * blockDim.x + threadIdx.x;
    if (i >= e) return;
    int d = dst[i];
    int p = atomicAdd(&cursor[d], 1);
    src_sorted[p] = src[i];
}

// K6: layer-1 propagation as gather on raw 4-channel x (one thread per node)
__global__ void k_gather1(const int* __restrict__ off, const int* __restrict__ src_sorted,
                          const float* __restrict__ dinv, const float* __restrict__ x,
                          float* xp, int n) {
    int v = blockIdx.x * blockDim.x + threadIdx.x;
    if (v >= n) return;
    float dv = dinv[v];
    const float4* x4 = (const float4*)x;
    float4 xv = x4[v];
    float sl = dv * dv;              // self-loop norm
    float a0 = sl * xv.x, a1 = sl * xv.y, a2 = sl * xv.z, a3 = sl * xv.w;
    int e0 = off[v], e1 = off[v + 1];
    for (int e = e0; e < e1; e++) {
        int s = src_sorted[e];
        float nrm = dinv[s] * dv;
        float4 xs = x4[s];
        a0 = fmaf(nrm, xs.x, a0); a1 = fmaf(nrm, xs.y, a1);
        a2 = fmaf(nrm, xs.z, a2); a3 = fmaf(nrm, xs.w, a3);
    }
    float4* xp4 = (float4*)xp;
    xp4[v] = make_float4(a0, a1, a2, a3);
}

// K7: f1 = relu(xp @ W1 + b1)
__global__ void k_f1(const float* __restrict__ xp, const float* __restrict__ W1,
                     const float* __restrict__ b1, float* f1, int n) {
    int i = blockIdx.x * blockDim.x + threadIdx.x;
    if (i >= n * HID) return;
    int v = i >> 7, c = i & (HID - 1);
    const float4* xr = (const float4*)(xp + v * IN_C);
    float4 xv = *xr;
    float s = fmaf(xv.x, W1[c],
              fmaf(xv.y, W1[HID + c],
              fmaf(xv.z, W1[2 * HID + c],
              fmaf(xv.w, W1[3 * HID + c], b1[c]))));
    f1[i] = s > 0.0f ? s : 0.0f;
}

// K8: layer-2 propagation as gather: one 128-thread block per node.
__global__ __launch_bounds__(HID) void k_gather2(
        const int* __restrict__ off, const int* __restrict__ src_sorted,
        const float* __restrict__ dinv, const float* __restrict__ f1,
        float* acc2, int n) {
    int v = blockIdx.x;
    if (v >= n) return;
    int c = threadIdx.x;
    float dv = dinv[v];
    float acc = dv * dv * f1[(long)v * HID + c];   // self-loop term
    int e0 = off[v], e1 = off[v + 1];
    for (int e = e0; e < e1; e++) {
        int s = src_sorted[e];
        float nrm = dinv[s] * dv;
        acc = fmaf(nrm, f1[(long)s * HID + c], acc);
    }
    acc2[(long)v * HID + c] = acc;
}

// K9: fused f2 = relu(acc2 @ W2 + b2) + segment-sum pool (batch sorted).
__global__ __launch_bounds__(HID) void k_mm2_pool(
        const float* __restrict__ acc2, const float* __restrict__ W2,
        const float* __restrict__ b2, const int* __restrict__ batch,
        float* out, int n) {
    int c = threadIdx.x;                 // 0..127
    int v0 = blockIdx.x * POOL_NODES;
    if (v0 >= n) return;

    float wcol[HID];
#pragma unroll
    for (int k = 0; k < HID; k++) wcol[k] = W2[k * HID + c];
    float bc = b2[c];

    int vend = v0 + POOL_NODES;
    if (vend > n) vend = n;

    float sum = 0.0f;
    int cur = batch[v0];
    for (int v = v0; v < vend; v++) {
        const float* arow = acc2 + (long)v * HID;
        float s = bc;
#pragma unroll
        for (int k = 0; k < HID; k++) s = fmaf(arow[k], wcol[k], s);
        s = s > 0.0f ? s : 0.0f;
        int b = batch[v];                // wave-uniform
        if (b != cur) {
            atomicAdd(&out[cur * HID + c], sum);
            sum = 0.0f;
            cur = b;
        }
        sum += s;
    }
    atomicAdd(&out[cur * HID + c], sum);
}

// K10: out[b][c] /= max(cnt[b], 1)
__global__ void k_div(float* out, const int* __restrict__ cnt, int outsz) {
    int i = blockIdx.x * blockDim.x + threadIdx.x;
    if (i < outsz) {
        int b = i >> 7;
        float cf = (float)cnt[b];
        out[i] = out[i] / fmaxf(cf, 1.0f);
    }
}

extern "C" void kernel_launch(void* const* d_in, const int* in_sizes, int n_in,
                              void* d_out, int out_size, void* d_ws, size_t ws_size,
                              hipStream_t stream) {
    const float* x   = (const float*)d_in[0];
    const int* ei    = (const int*)d_in[1];   // [2, E] flat: src then dst
    const int* batch = (const int*)d_in[2];
    const float* W1  = (const float*)d_in[3];
    const float* b1  = (const float*)d_in[4];
    const float* W2  = (const float*)d_in[5];
    const float* b2  = (const float*)d_in[6];
    float* out = (float*)d_out;

    int n  = in_sizes[0] / IN_C;
    int e  = in_sizes[1] / 2;
    int bg = out_size / HID;
    const int* src = ei;
    const int* dst = ei + e;

    size_t off_b = 0;
    char* base = (char*)d_ws;
    auto carve = [&](size_t bytes) -> void* {
        void* p = base + off_b;
        off_b += (bytes + 255) & ~(size_t)255;
        return p;
    };
    int nbScan = (n + SCAN_CHUNK - 1) / SCAN_CHUNK;
    int*   deg_i      = (int*)carve((size_t)n * 4);
    int*   off        = (int*)carve((size_t)(n + 1) * 4);
    int*   cursor     = (int*)carve((size_t)n * 4);
    int*   src_sorted = (int*)carve((size_t)e * 4);
    float* dinv       = (float*)carve((size_t)n * 4);
    int*   bsum       = (int*)carve((size_t)nbScan * 4);
    float* xp         = (float*)carve((size_t)n * IN_C * 4);
    float* f1         = (float*)carve((size_t)n * HID * 4);
    float* acc2       = (float*)carve((size_t)n * HID * 4);
    int*   cnt        = (int*)carve((size_t)bg * 4);
    (void)ws_size;

    int gN = (n + TPB - 1) / TPB;
    int gE = (e + TPB - 1) / TPB;

    k_init<<<gN, TPB, 0, stream>>>(deg_i, out, n, out_size);
    k_hist<<<gE, TPB, 0, stream>>>(dst, deg_i, e);
    k_cnt<<<1, 64, 0, stream>>>(batch, cnt, n, bg);
    k_scan_part<<<nbScan, SCAN_TPB, 0, stream>>>(deg_i, bsum, n);
    k_scan_bsum<<<1, 1024, 0, stream>>>(bsum, nbScan);
    k_scan_final<<<nbScan, SCAN_TPB, 0, stream>>>(deg_i, bsum, off, cursor, dinv, n, e);
    k_fillpos<<<gE, TPB, 0, stream>>>(src, dst, cursor, src_sorted, e);
    k_gather1<<<gN, TPB, 0, stream>>>(off, src_sorted, dinv, x, xp, n);
    k_f1<<<(n * HID + TPB - 1) / TPB, TPB, 0, stream>>>(xp, W1, b1, f1, n);
    k_gather2<<<n, HID, 0, stream>>>(off, src_sorted, dinv, f1, acc2, n);
    k_mm2_pool<<<(n + POOL_NODES - 1) / POOL_NODES, HID, 0, stream>>>(acc2, W2, b2, batch, out, n);
    k_div<<<(out_size + TPB - 1) / TPB, TPB, 0, stream>>>(out, cnt, out_size);
}

// Round 4
// 635.614 us; speedup vs baseline: 2.6246x; 1.1108x over previous
//
#include <hip/hip_runtime.h>

#define TPB 256
#define HID 128
#define IN_C 4
#define SCAN_TPB 256
#define SCAN_CHUNK 1024   // 4 elements per thread
#define GEMM_TPB 256
#define TILE_N 64

// ---------------------------------------------------------------------------
// K0: zero deg_i and out
__global__ void k_init(int* deg_i, float* out, int n, int outsz) {
    int i = blockIdx.x * blockDim.x + threadIdx.x;
    if (i < n) deg_i[i] = 0;
    if (i < outsz) out[i] = 0.0f;
}

// K1: in-degree histogram (int atomics, random dsts -> low contention)
__global__ void k_hist(const int* __restrict__ dst, int* deg_i, int e) {
    int i = blockIdx.x * blockDim.x + threadIdx.x;
    if (i < e) atomicAdd(&deg_i[dst[i]], 1);
}

// K2: per-graph node counts via binary search on sorted batch (no atomics)
__global__ void k_cnt(const int* __restrict__ batch, int* cnt, int n, int bg) {
    int b = blockIdx.x * blockDim.x + threadIdx.x;
    if (b >= bg) return;
    int lo0 = 0, hi0 = n;
    while (lo0 < hi0) { int m = (lo0 + hi0) >> 1; if (batch[m] < b) lo0 = m + 1; else hi0 = m; }
    int lo1 = lo0, hi1 = n;
    while (lo1 < hi1) { int m = (lo1 + hi1) >> 1; if (batch[m] < b + 1) lo1 = m + 1; else hi1 = m; }
    cnt[b] = lo1 - lo0;
}

// K3a: per-block sums of deg_i (block = SCAN_CHUNK elements)
__global__ __launch_bounds__(SCAN_TPB) void k_scan_part(const int* __restrict__ deg_i,
                                                        int* bsum, int n) {
    __shared__ int red[SCAN_TPB];
    int b = blockIdx.x, t = threadIdx.x;
    int base = b * SCAN_CHUNK + t * 4;
    int s = 0;
#pragma unroll
    for (int k = 0; k < 4; k++) {
        int i = base + k;
        if (i < n) s += deg_i[i];
    }
    red[t] = s;
    __syncthreads();
    for (int d = SCAN_TPB / 2; d > 0; d >>= 1) {
        if (t < d) red[t] += red[t + d];
        __syncthreads();
    }
    if (t == 0) bsum[b] = red[0];
}

// K3b: single-block exclusive scan of block sums
__global__ __launch_bounds__(1024) void k_scan_bsum(int* bsum, int nb) {
    __shared__ int red[1024];
    int t = threadIdx.x;
    int carry = 0;
    for (int base = 0; base < nb; base += 1024) {
        int i = base + t;
        int v = (i < nb) ? bsum[i] : 0;
        red[t] = v;
        __syncthreads();
        for (int d = 1; d < 1024; d <<= 1) {
            int x = 0;
            if (t >= d) x = red[t - d];
            __syncthreads();
            if (t >= d) red[t] += x;
            __syncthreads();
        }
        int tot = red[1023];
        if (i < nb) bsum[i] = carry + red[t] - v;   // exclusive
        carry += tot;
        __syncthreads();
    }
}

// K3c: final scan pass -> off, cursor; fused dinv = rsqrt(deg+1)
__global__ __launch_bounds__(SCAN_TPB) void k_scan_final(
        const int* __restrict__ deg_i, const int* __restrict__ bsum,
        int* off, int* cursor, float* dinv, int n, int e) {
    __shared__ int red[SCAN_TPB];
    int b = blockIdx.x, t = threadIdx.x;
    int base = b * SCAN_CHUNK + t * 4;
    int v[4];
    int s = 0;
#pragma unroll
    for (int k = 0; k < 4; k++) {
        int i = base + k;
        v[k] = (i < n) ? deg_i[i] : 0;
        s += v[k];
    }
    red[t] = s;
    __syncthreads();
    for (int d = 1; d < SCAN_TPB; d <<= 1) {
        int x = 0;
        if (t >= d) x = red[t - d];
        __syncthreads();
        if (t >= d) red[t] += x;
        __syncthreads();
    }
    int run = bsum[b] + red[t] - s;
#pragma unroll
    for (int k = 0; k < 4; k++) {
        int i = base + k;
        if (i < n) {
            off[i] = run;
            cursor[i] = run;
            dinv[i] = rsqrtf((float)v[k] + 1.0f);
            run += v[k];
        }
    }
    if (b == 0 && t == 0) off[n] = e;
}

// K5: counting-sort fill: src_sorted grouped by dst
__global__ void k_fillpos(const int* __restrict__ src, const int* __restrict__ dst,
                          int* cursor, int* src_sorted, int e) {
    int i = blockIdx.x * blockDim.x + threadIdx.x;
    if (i >= e) return;
    int d = dst[i];
    int p = atomicAdd(&cursor[d], 1);
    src_sorted[p] = src[i];
}

// K6: layer-1 propagation as gather on raw 4-channel x (one thread per node)
__global__ void k_gather1(const int* __restrict__ off, const int* __restrict__ src_sorted,
                          const float* __restrict__ dinv, const float* __restrict__ x,
                          float* xp, int n) {
    int v = blockIdx.x * blockDim.x + threadIdx.x;
    if (v >= n) return;
    float dv = dinv[v];
    const float4* x4 = (const float4*)x;
    float4 xv = x4[v];
    float sl = dv * dv;
    float a0 = sl * xv.x, a1 = sl * xv.y, a2 = sl * xv.z, a3 = sl * xv.w;
    int e0 = off[v], e1 = off[v + 1];
    for (int e = e0; e < e1; e++) {
        int s = src_sorted[e];
        float nrm = dinv[s] * dv;
        float4 xs = x4[s];
        a0 = fmaf(nrm, xs.x, a0); a1 = fmaf(nrm, xs.y, a1);
        a2 = fmaf(nrm, xs.z, a2); a3 = fmaf(nrm, xs.w, a3);
    }
    float4* xp4 = (float4*)xp;
    xp4[v] = make_float4(a0, a1, a2, a3);
}

// K7: f1 = relu(xp @ W1 + b1)
__global__ void k_f1(const float* __restrict__ xp, const float* __restrict__ W1,
                     const float* __restrict__ b1, float* f1, int n) {
    int i = blockIdx.x * blockDim.x + threadIdx.x;
    if (i >= n * HID) return;
    int v = i >> 7, c = i & (HID - 1);
    const float4* xr = (const float4*)(xp + v * IN_C);
    float4 xv = *xr;
    float s = fmaf(xv.x, W1[c],
              fmaf(xv.y, W1[HID + c],
              fmaf(xv.z, W1[2 * HID + c],
              fmaf(xv.w, W1[3 * HID + c], b1[c]))));
    f1[i] = s > 0.0f ? s : 0.0f;
}

// K8: layer-2 propagation as gather: one 128-thread block per node.
__global__ __launch_bounds__(HID) void k_gather2(
        const int* __restrict__ off, const int* __restrict__ src_sorted,
        const float* __restrict__ dinv, const float* __restrict__ f1,
        float* acc2, int n) {
    int v = blockIdx.x;
    if (v >= n) return;
    int c = threadIdx.x;
    float dv = dinv[v];
    float acc = dv * dv * f1[(long)v * HID + c];   // self-loop term
    int e0 = off[v], e1 = off[v + 1];
    for (int e = e0; e < e1; e++) {
        int s = src_sorted[e];
        float nrm = dinv[s] * dv;
        acc = fmaf(nrm, f1[(long)s * HID + c], acc);
    }
    acc2[(long)v * HID + c] = acc;
}

// K9: LDS-tiled register-blocked GEMM + fused bias/ReLU/segment-pool.
// Block: 64-node x 128-ch tile, 256 threads, each owns 8 nodes x 4 channels.
// LDS: A-tile 64x132 (pad) = 33.8 KB + W2 chunk 64x128 = 32 KB -> 2 blocks/CU.
__global__ __launch_bounds__(GEMM_TPB, 2) void k_mm2_pool(
        const float* __restrict__ acc2, const float* __restrict__ W2,
        const float* __restrict__ b2, const int* __restrict__ batch,
        float* out, int n) {
    __shared__ float As[TILE_N][132];   // node-major, pad 128->132 words
    __shared__ float Ws[64][128];       // one 64-row k-chunk of W2
    __shared__ int bch[TILE_N];

    int t = threadIdx.x;
    int v0 = blockIdx.x * TILE_N;
    int cg = t & 31;          // channel quad: channels 4cg..4cg+3
    int ng = t >> 5;          // node octet: nodes 8ng..8ng+7
    int nd0 = ng * 8;

    // stage A tile: straight row copy, fully coalesced (32 f4 per row)
#pragma unroll
    for (int j = 0; j < 8; j++) {
        int fi = t + GEMM_TPB * j;          // 0..2047
        int nd = fi >> 5, kq = fi & 31;
        int v = v0 + nd;
        if (v < n) {
            float4 a = ((const float4*)acc2)[(size_t)v * 32 + kq];
            *(float4*)&As[nd][kq * 4] = a;
        }
    }
    if (t < TILE_N) {
        int v = v0 + t;
        bch[t] = (v < n) ? batch[v] : -1;
    }

    float4 acc[8];
#pragma unroll
    for (int i = 0; i < 8; i++) acc[i] = make_float4(0.f, 0.f, 0.f, 0.f);

    for (int ch = 0; ch < 2; ch++) {
        __syncthreads();                     // Ws free to overwrite / As staged
#pragma unroll
        for (int j = 0; j < 8; j++) {
            int fi = t + GEMM_TPB * j;       // 0..2047 float4s
            ((float4*)Ws)[fi] = ((const float4*)W2)[ch * 2048 + fi];
        }
        __syncthreads();
#pragma unroll
        for (int k4 = 0; k4 < 16; k4++) {
            int k0 = k4 * 4;
            float4 w0 = *(float4*)&Ws[k0 + 0][cg * 4];
            float4 w1 = *(float4*)&Ws[k0 + 1][cg * 4];
            float4 w2 = *(float4*)&Ws[k0 + 2][cg * 4];
            float4 w3 = *(float4*)&Ws[k0 + 3][cg * 4];
#pragma unroll
            for (int i = 0; i < 8; i++) {
                float4 a = *(float4*)&As[nd0 + i][ch * 64 + k0];
                acc[i].x = fmaf(a.x, w0.x, acc[i].x);
                acc[i].y = fmaf(a.x, w0.y, acc[i].y);
                acc[i].z = fmaf(a.x, w0.z, acc[i].z);
                acc[i].w = fmaf(a.x, w0.w, acc[i].w);
                acc[i].x = fmaf(a.y, w1.x, acc[i].x);
                acc[i].y = fmaf(a.y, w1.y, acc[i].y);
                acc[i].z = fmaf(a.y, w1.z, acc[i].z);
                acc[i].w = fmaf(a.y, w1.w, acc[i].w);
                acc[i].x = fmaf(a.z, w2.x, acc[i].x);
                acc[i].y = fmaf(a.z, w2.y, acc[i].y);
                acc[i].z = fmaf(a.z, w2.z, acc[i].z);
                acc[i].w = fmaf(a.z, w2.w, acc[i].w);
                acc[i].x = fmaf(a.w, w3.x, acc[i].x);
                acc[i].y = fmaf(a.w, w3.y, acc[i].y);
                acc[i].z = fmaf(a.w, w3.z, acc[i].z);
                acc[i].w = fmaf(a.w, w3.w, acc[i].w);
            }
        }
    }

    // epilogue: bias + relu + segment run-accumulate (batch sorted)
    float4 bb = *(const float4*)(b2 + cg * 4);
    int curb = -1;
    float4 run = make_float4(0.f, 0.f, 0.f, 0.f);
    for (int i = 0; i < 8; i++) {
        int b = bch[nd0 + i];
        if (b < 0) break;                    // invalid nodes are a suffix
        if (b != curb) {
            if (curb >= 0) {
                float* o = out + (size_t)curb * HID + cg * 4;
                atomicAdd(o + 0, run.x); atomicAdd(o + 1, run.y);
                atomicAdd(o + 2, run.z); atomicAdd(o + 3, run.w);
            }
            run = make_float4(0.f, 0.f, 0.f, 0.f);
            curb = b;
        }
        float fx = acc[i].x + bb.x; run.x += fx > 0.f ? fx : 0.f;
        float fy = acc[i].y + bb.y; run.y += fy > 0.f ? fy : 0.f;
        float fz = acc[i].z + bb.z; run.z += fz > 0.f ? fz : 0.f;
        float fw = acc[i].w + bb.w; run.w += fw > 0.f ? fw : 0.f;
    }
    if (curb >= 0) {
        float* o = out + (size_t)curb * HID + cg * 4;
        atomicAdd(o + 0, run.x); atomicAdd(o + 1, run.y);
        atomicAdd(o + 2, run.z); atomicAdd(o + 3, run.w);
    }
}

// K10: out[b][c] /= max(cnt[b], 1)
__global__ void k_div(float* out, const int* __restrict__ cnt, int outsz) {
    int i = blockIdx.x * blockDim.x + threadIdx.x;
    if (i < outsz) {
        int b = i >> 7;
        float cf = (float)cnt[b];
        out[i] = out[i] / fmaxf(cf, 1.0f);
    }
}

extern "C" void kernel_launch(void* const* d_in, const int* in_sizes, int n_in,
                              void* d_out, int out_size, void* d_ws, size_t ws_size,
                              hipStream_t stream) {
    const float* x   = (const float*)d_in[0];
    const int* ei    = (const int*)d_in[1];   // [2, E] flat: src then dst
    const int* batch = (const int*)d_in[2];
    const float* W1  = (const float*)d_in[3];
    const float* b1  = (const float*)d_in[4];
    const float* W2  = (const float*)d_in[5];
    const float* b2  = (const float*)d_in[6];
    float* out = (float*)d_out;

    int n  = in_sizes[0] / IN_C;
    int e  = in_sizes[1] / 2;
    int bg = out_size / HID;
    const int* src = ei;
    const int* dst = ei + e;

    size_t off_b = 0;
    char* base = (char*)d_ws;
    auto carve = [&](size_t bytes) -> void* {
        void* p = base + off_b;
        off_b += (bytes + 255) & ~(size_t)255;
        return p;
    };
    int nbScan = (n + SCAN_CHUNK - 1) / SCAN_CHUNK;
    int*   deg_i      = (int*)carve((size_t)n * 4);
    int*   off        = (int*)carve((size_t)(n + 1) * 4);
    int*   cursor     = (int*)carve((size_t)n * 4);
    int*   src_sorted = (int*)carve((size_t)e * 4);
    float* dinv       = (float*)carve((size_t)n * 4);
    int*   bsum       = (int*)carve((size_t)nbScan * 4);
    float* xp         = (float*)carve((size_t)n * IN_C * 4);
    float* f1         = (float*)carve((size_t)n * HID * 4);
    float* acc2       = (float*)carve((size_t)n * HID * 4);
    int*   cnt        = (int*)carve((size_t)bg * 4);
    (void)ws_size;

    int gN = (n + TPB - 1) / TPB;
    int gE = (e + TPB - 1) / TPB;

    k_init<<<gN, TPB, 0, stream>>>(deg_i, out, n, out_size);
    k_hist<<<gE, TPB, 0, stream>>>(dst, deg_i, e);
    k_cnt<<<1, 64, 0, stream>>>(batch, cnt, n, bg);
    k_scan_part<<<nbScan, SCAN_TPB, 0, stream>>>(deg_i, bsum, n);
    k_scan_bsum<<<1, 1024, 0, stream>>>(bsum, nbScan);
    k_scan_final<<<nbScan, SCAN_TPB, 0, stream>>>(deg_i, bsum, off, cursor, dinv, n, e);
    k_fillpos<<<gE, TPB, 0, stream>>>(src, dst, cursor, src_sorted, e);
    k_gather1<<<gN, TPB, 0, stream>>>(off, src_sorted, dinv, x, xp, n);
    k_f1<<<(n * HID + TPB - 1) / TPB, TPB, 0, stream>>>(xp, W1, b1, f1, n);
    k_gather2<<<n, HID, 0, stream>>>(off, src_sorted, dinv, f1, acc2, n);
    k_mm2_pool<<<(n + TILE_N - 1) / TILE_N, GEMM_TPB, 0, stream>>>(acc2, W2, b2, batch, out, n);
    k_div<<<(out_size + TPB - 1) / TPB, TPB, 0, stream>>>(out, cnt, out_size);
}

// Round 5
// 576.997 us; speedup vs baseline: 2.8913x; 1.1016x over previous
//
#include <hip/hip_runtime.h>

#define TPB 256
#define HID 128
#define IN_C 4
#define SCAN_TPB 256
#define SCAN_CHUNK 1024   // 4 elements per thread
#define GEMM_TPB 256
#define TILE_N 64

// ---------------------------------------------------------------------------
// K0: zero deg_i and out
__global__ void k_init(int* deg_i, float* out, int n, int outsz) {
    int i = blockIdx.x * blockDim.x + threadIdx.x;
    if (i < n) deg_i[i] = 0;
    if (i < outsz) out[i] = 0.0f;
}

// K1: in-degree histogram (int atomics, random dsts -> low contention)
__global__ void k_hist(const int* __restrict__ dst, int* deg_i, int e) {
    int i = blockIdx.x * blockDim.x + threadIdx.x;
    if (i < e) atomicAdd(&deg_i[dst[i]], 1);
}

// K2: per-graph node counts via binary search on sorted batch (no atomics)
__global__ void k_cnt(const int* __restrict__ batch, int* cnt, int n, int bg) {
    int b = blockIdx.x * blockDim.x + threadIdx.x;
    if (b >= bg) return;
    int lo0 = 0, hi0 = n;
    while (lo0 < hi0) { int m = (lo0 + hi0) >> 1; if (batch[m] < b) lo0 = m + 1; else hi0 = m; }
    int lo1 = lo0, hi1 = n;
    while (lo1 < hi1) { int m = (lo1 + hi1) >> 1; if (batch[m] < b + 1) lo1 = m + 1; else hi1 = m; }
    cnt[b] = lo1 - lo0;
}

// K3a: per-block sums of deg_i (block = SCAN_CHUNK elements)
__global__ __launch_bounds__(SCAN_TPB) void k_scan_part(const int* __restrict__ deg_i,
                                                        int* bsum, int n) {
    __shared__ int red[SCAN_TPB];
    int b = blockIdx.x, t = threadIdx.x;
    int base = b * SCAN_CHUNK + t * 4;
    int s = 0;
#pragma unroll
    for (int k = 0; k < 4; k++) {
        int i = base + k;
        if (i < n) s += deg_i[i];
    }
    red[t] = s;
    __syncthreads();
    for (int d = SCAN_TPB / 2; d > 0; d >>= 1) {
        if (t < d) red[t] += red[t + d];
        __syncthreads();
    }
    if (t == 0) bsum[b] = red[0];
}

// K3b: single-block exclusive scan of block sums
__global__ __launch_bounds__(1024) void k_scan_bsum(int* bsum, int nb) {
    __shared__ int red[1024];
    int t = threadIdx.x;
    int carry = 0;
    for (int base = 0; base < nb; base += 1024) {
        int i = base + t;
        int v = (i < nb) ? bsum[i] : 0;
        red[t] = v;
        __syncthreads();
        for (int d = 1; d < 1024; d <<= 1) {
            int x = 0;
            if (t >= d) x = red[t - d];
            __syncthreads();
            if (t >= d) red[t] += x;
            __syncthreads();
        }
        int tot = red[1023];
        if (i < nb) bsum[i] = carry + red[t] - v;   // exclusive
        carry += tot;
        __syncthreads();
    }
}

// K3c: final scan pass -> off, cursor; fused dinv = rsqrt(deg+1)
__global__ __launch_bounds__(SCAN_TPB) void k_scan_final(
        const int* __restrict__ deg_i, const int* __restrict__ bsum,
        int* off, int* cursor, float* dinv, int n, int e) {
    __shared__ int red[SCAN_TPB];
    int b = blockIdx.x, t = threadIdx.x;
    int base = b * SCAN_CHUNK + t * 4;
    int v[4];
    int s = 0;
#pragma unroll
    for (int k = 0; k < 4; k++) {
        int i = base + k;
        v[k] = (i < n) ? deg_i[i] : 0;
        s += v[k];
    }
    red[t] = s;
    __syncthreads();
    for (int d = 1; d < SCAN_TPB; d <<= 1) {
        int x = 0;
        if (t >= d) x = red[t - d];
        __syncthreads();
        if (t >= d) red[t] += x;
        __syncthreads();
    }
    int run = bsum[b] + red[t] - s;
#pragma unroll
    for (int k = 0; k < 4; k++) {
        int i = base + k;
        if (i < n) {
            off[i] = run;
            cursor[i] = run;
            dinv[i] = rsqrtf((float)v[k] + 1.0f);
            run += v[k];
        }
    }
    if (b == 0 && t == 0) off[n] = e;
}

// K5: counting-sort fill: src_sorted grouped by dst
__global__ void k_fillpos(const int* __restrict__ src, const int* __restrict__ dst,
                          int* cursor, int* src_sorted, int e) {
    int i = blockIdx.x * blockDim.x + threadIdx.x;
    if (i >= e) return;
    int d = dst[i];
    int p = atomicAdd(&cursor[d], 1);
    src_sorted[p] = src[i];
}

// K6: layer-1 propagation as gather on raw 4-channel x; unroll x4 for MLP
__global__ void k_gather1(const int* __restrict__ off, const int* __restrict__ src_sorted,
                          const float* __restrict__ dinv, const float* __restrict__ x,
                          float* xp, int n) {
    int v = blockIdx.x * blockDim.x + threadIdx.x;
    if (v >= n) return;
    float dv = dinv[v];
    const float4* x4 = (const float4*)x;
    float4 xv = x4[v];
    float sl = dv * dv;
    float4 A = make_float4(sl * xv.x, sl * xv.y, sl * xv.z, sl * xv.w);
    float4 B = make_float4(0.f, 0.f, 0.f, 0.f);
    float4 C = make_float4(0.f, 0.f, 0.f, 0.f);
    float4 D = make_float4(0.f, 0.f, 0.f, 0.f);
    int e0 = off[v], e1 = off[v + 1];
    int e = e0;
    for (; e + 4 <= e1; e += 4) {
        int s0 = src_sorted[e], s1 = src_sorted[e + 1];
        int s2 = src_sorted[e + 2], s3 = src_sorted[e + 3];
        float n0 = dinv[s0] * dv, n1 = dinv[s1] * dv;
        float n2 = dinv[s2] * dv, n3 = dinv[s3] * dv;
        float4 r0 = x4[s0], r1 = x4[s1], r2 = x4[s2], r3 = x4[s3];
        A.x = fmaf(n0, r0.x, A.x); A.y = fmaf(n0, r0.y, A.y);
        A.z = fmaf(n0, r0.z, A.z); A.w = fmaf(n0, r0.w, A.w);
        B.x = fmaf(n1, r1.x, B.x); B.y = fmaf(n1, r1.y, B.y);
        B.z = fmaf(n1, r1.z, B.z); B.w = fmaf(n1, r1.w, B.w);
        C.x = fmaf(n2, r2.x, C.x); C.y = fmaf(n2, r2.y, C.y);
        C.z = fmaf(n2, r2.z, C.z); C.w = fmaf(n2, r2.w, C.w);
        D.x = fmaf(n3, r3.x, D.x); D.y = fmaf(n3, r3.y, D.y);
        D.z = fmaf(n3, r3.z, D.z); D.w = fmaf(n3, r3.w, D.w);
    }
    for (; e < e1; e++) {
        int s = src_sorted[e];
        float nm = dinv[s] * dv;
        float4 r = x4[s];
        A.x = fmaf(nm, r.x, A.x); A.y = fmaf(nm, r.y, A.y);
        A.z = fmaf(nm, r.z, A.z); A.w = fmaf(nm, r.w, A.w);
    }
    float4 o;
    o.x = (A.x + B.x) + (C.x + D.x);
    o.y = (A.y + B.y) + (C.y + D.y);
    o.z = (A.z + B.z) + (C.z + D.z);
    o.w = (A.w + B.w) + (C.w + D.w);
    ((float4*)xp)[v] = o;
}

// K7: f1 = relu(xp @ W1 + b1)
__global__ void k_f1(const float* __restrict__ xp, const float* __restrict__ W1,
                     const float* __restrict__ b1, float* f1, int n) {
    int i = blockIdx.x * blockDim.x + threadIdx.x;
    if (i >= n * HID) return;
    int v = i >> 7, c = i & (HID - 1);
    const float4* xr = (const float4*)(xp + v * IN_C);
    float4 xv = *xr;
    float s = fmaf(xv.x, W1[c],
              fmaf(xv.y, W1[HID + c],
              fmaf(xv.z, W1[2 * HID + c],
              fmaf(xv.w, W1[3 * HID + c], b1[c]))));
    f1[i] = s > 0.0f ? s : 0.0f;
}

// K8: layer-2 gather: one WAVE per node, float2 per lane (512B row / instr),
// edge loop unrolled x4 with independent accumulators -> 4 rows in flight.
__global__ __launch_bounds__(256) void k_gather2(
        const int* __restrict__ off, const int* __restrict__ src_sorted,
        const float* __restrict__ dinv, const float* __restrict__ f1,
        float* acc2, int n) {
    int wv = threadIdx.x >> 6;           // wave id 0..3
    int ln = threadIdx.x & 63;           // lane
    int v = blockIdx.x * 4 + wv;
    if (v >= n) return;
    float dv = dinv[v];
    const float2* f2 = (const float2*)f1;   // row = 64 float2
    float2 self = f2[(size_t)v * 64 + ln];
    float sl = dv * dv;
    float ax = sl * self.x, ay = sl * self.y;
    float bx = 0.f, by = 0.f, cx = 0.f, cy = 0.f, dx = 0.f, dy = 0.f;
    int e0 = off[v], e1 = off[v + 1];
    int e = e0;
    for (; e + 4 <= e1; e += 4) {
        int s0 = src_sorted[e],     s1 = src_sorted[e + 1];
        int s2 = src_sorted[e + 2], s3 = src_sorted[e + 3];
        float n0 = dinv[s0] * dv, n1 = dinv[s1] * dv;
        float n2 = dinv[s2] * dv, n3 = dinv[s3] * dv;
        float2 r0 = f2[(size_t)s0 * 64 + ln];
        float2 r1 = f2[(size_t)s1 * 64 + ln];
        float2 r2 = f2[(size_t)s2 * 64 + ln];
        float2 r3 = f2[(size_t)s3 * 64 + ln];
        ax = fmaf(n0, r0.x, ax); ay = fmaf(n0, r0.y, ay);
        bx = fmaf(n1, r1.x, bx); by = fmaf(n1, r1.y, by);
        cx = fmaf(n2, r2.x, cx); cy = fmaf(n2, r2.y, cy);
        dx = fmaf(n3, r3.x, dx); dy = fmaf(n3, r3.y, dy);
    }
    for (; e < e1; e++) {
        int s = src_sorted[e];
        float nm = dinv[s] * dv;
        float2 r = f2[(size_t)s * 64 + ln];
        ax = fmaf(nm, r.x, ax); ay = fmaf(nm, r.y, ay);
    }
    float2 o;
    o.x = (ax + bx) + (cx + dx);
    o.y = (ay + by) + (cy + dy);
    ((float2*)acc2)[(size_t)v * 64 + ln] = o;
}

// K9: LDS-tiled register-blocked GEMM + fused bias/ReLU/segment-pool.
__global__ __launch_bounds__(GEMM_TPB, 2) void k_mm2_pool(
        const float* __restrict__ acc2, const float* __restrict__ W2,
        const float* __restrict__ b2, const int* __restrict__ batch,
        float* out, int n) {
    __shared__ float As[TILE_N][132];   // node-major, pad 128->132 words
    __shared__ float Ws[64][128];       // one 64-row k-chunk of W2
    __shared__ int bch[TILE_N];

    int t = threadIdx.x;
    int v0 = blockIdx.x * TILE_N;
    int cg = t & 31;          // channel quad: channels 4cg..4cg+3
    int ng = t >> 5;          // node octet: nodes 8ng..8ng+7
    int nd0 = ng * 8;

#pragma unroll
    for (int j = 0; j < 8; j++) {
        int fi = t + GEMM_TPB * j;          // 0..2047
        int nd = fi >> 5, kq = fi & 31;
        int v = v0 + nd;
        if (v < n) {
            float4 a = ((const float4*)acc2)[(size_t)v * 32 + kq];
            *(float4*)&As[nd][kq * 4] = a;
        }
    }
    if (t < TILE_N) {
        int v = v0 + t;
        bch[t] = (v < n) ? batch[v] : -1;
    }

    float4 acc[8];
#pragma unroll
    for (int i = 0; i < 8; i++) acc[i] = make_float4(0.f, 0.f, 0.f, 0.f);

    for (int ch = 0; ch < 2; ch++) {
        __syncthreads();
#pragma unroll
        for (int j = 0; j < 8; j++) {
            int fi = t + GEMM_TPB * j;
            ((float4*)Ws)[fi] = ((const float4*)W2)[ch * 2048 + fi];
        }
        __syncthreads();
#pragma unroll
        for (int k4 = 0; k4 < 16; k4++) {
            int k0 = k4 * 4;
            float4 w0 = *(float4*)&Ws[k0 + 0][cg * 4];
            float4 w1 = *(float4*)&Ws[k0 + 1][cg * 4];
            float4 w2 = *(float4*)&Ws[k0 + 2][cg * 4];
            float4 w3 = *(float4*)&Ws[k0 + 3][cg * 4];
#pragma unroll
            for (int i = 0; i < 8; i++) {
                float4 a = *(float4*)&As[nd0 + i][ch * 64 + k0];
                acc[i].x = fmaf(a.x, w0.x, acc[i].x);
                acc[i].y = fmaf(a.x, w0.y, acc[i].y);
                acc[i].z = fmaf(a.x, w0.z, acc[i].z);
                acc[i].w = fmaf(a.x, w0.w, acc[i].w);
                acc[i].x = fmaf(a.y, w1.x, acc[i].x);
                acc[i].y = fmaf(a.y, w1.y, acc[i].y);
                acc[i].z = fmaf(a.y, w1.z, acc[i].z);
                acc[i].w = fmaf(a.y, w1.w, acc[i].w);
                acc[i].x = fmaf(a.z, w2.x, acc[i].x);
                acc[i].y = fmaf(a.z, w2.y, acc[i].y);
                acc[i].z = fmaf(a.z, w2.z, acc[i].z);
                acc[i].w = fmaf(a.z, w2.w, acc[i].w);
                acc[i].x = fmaf(a.w, w3.x, acc[i].x);
                acc[i].y = fmaf(a.w, w3.y, acc[i].y);
                acc[i].z = fmaf(a.w, w3.z, acc[i].z);
                acc[i].w = fmaf(a.w, w3.w, acc[i].w);
            }
        }
    }

    // epilogue: bias + relu + segment run-accumulate (batch sorted)
    float4 bb = *(const float4*)(b2 + cg * 4);
    int curb = -1;
    float4 run = make_float4(0.f, 0.f, 0.f, 0.f);
    for (int i = 0; i < 8; i++) {
        int b = bch[nd0 + i];
        if (b < 0) break;
        if (b != curb) {
            if (curb >= 0) {
                float* o = out + (size_t)curb * HID + cg * 4;
                atomicAdd(o + 0, run.x); atomicAdd(o + 1, run.y);
                atomicAdd(o + 2, run.z); atomicAdd(o + 3, run.w);
            }
            run = make_float4(0.f, 0.f, 0.f, 0.f);
            curb = b;
        }
        float fx = acc[i].x + bb.x; run.x += fx > 0.f ? fx : 0.f;
        float fy = acc[i].y + bb.y; run.y += fy > 0.f ? fy : 0.f;
        float fz = acc[i].z + bb.z; run.z += fz > 0.f ? fz : 0.f;
        float fw = acc[i].w + bb.w; run.w += fw > 0.f ? fw : 0.f;
    }
    if (curb >= 0) {
        float* o = out + (size_t)curb * HID + cg * 4;
        atomicAdd(o + 0, run.x); atomicAdd(o + 1, run.y);
        atomicAdd(o + 2, run.z); atomicAdd(o + 3, run.w);
    }
}

// K10: out[b][c] /= max(cnt[b], 1)
__global__ void k_div(float* out, const int* __restrict__ cnt, int outsz) {
    int i = blockIdx.x * blockDim.x + threadIdx.x;
    if (i < outsz) {
        int b = i >> 7;
        float cf = (float)cnt[b];
        out[i] = out[i] / fmaxf(cf, 1.0f);
    }
}

extern "C" void kernel_launch(void* const* d_in, const int* in_sizes, int n_in,
                              void* d_out, int out_size, void* d_ws, size_t ws_size,
                              hipStream_t stream) {
    const float* x   = (const float*)d_in[0];
    const int* ei    = (const int*)d_in[1];   // [2, E] flat: src then dst
    const int* batch = (const int*)d_in[2];
    const float* W1  = (const float*)d_in[3];
    const float* b1  = (const float*)d_in[4];
    const float* W2  = (const float*)d_in[5];
    const float* b2  = (const float*)d_in[6];
    float* out = (float*)d_out;

    int n  = in_sizes[0] / IN_C;
    int e  = in_sizes[1] / 2;
    int bg = out_size / HID;
    const int* src = ei;
    const int* dst = ei + e;

    size_t off_b = 0;
    char* base = (char*)d_ws;
    auto carve = [&](size_t bytes) -> void* {
        void* p = base + off_b;
        off_b += (bytes + 255) & ~(size_t)255;
        return p;
    };
    int nbScan = (n + SCAN_CHUNK - 1) / SCAN_CHUNK;
    int*   deg_i      = (int*)carve((size_t)n * 4);
    int*   off        = (int*)carve((size_t)(n + 1) * 4);
    int*   cursor     = (int*)carve((size_t)n * 4);
    int*   src_sorted = (int*)carve((size_t)e * 4);
    float* dinv       = (float*)carve((size_t)n * 4);
    int*   bsum       = (int*)carve((size_t)nbScan * 4);
    float* xp         = (float*)carve((size_t)n * IN_C * 4);
    float* f1         = (float*)carve((size_t)n * HID * 4);
    float* acc2       = (float*)carve((size_t)n * HID * 4);
    int*   cnt        = (int*)carve((size_t)bg * 4);
    (void)ws_size;

    int gN = (n + TPB - 1) / TPB;
    int gE = (e + TPB - 1) / TPB;

    k_init<<<gN, TPB, 0, stream>>>(deg_i, out, n, out_size);
    k_hist<<<gE, TPB, 0, stream>>>(dst, deg_i, e);
    k_cnt<<<1, 64, 0, stream>>>(batch, cnt, n, bg);
    k_scan_part<<<nbScan, SCAN_TPB, 0, stream>>>(deg_i, bsum, n);
    k_scan_bsum<<<1, 1024, 0, stream>>>(bsum, nbScan);
    k_scan_final<<<nbScan, SCAN_TPB, 0, stream>>>(deg_i, bsum, off, cursor, dinv, n, e);
    k_fillpos<<<gE, TPB, 0, stream>>>(src, dst, cursor, src_sorted, e);
    k_gather1<<<gN, TPB, 0, stream>>>(off, src_sorted, dinv, x, xp, n);
    k_f1<<<(n * HID + TPB - 1) / TPB, TPB, 0, stream>>>(xp, W1, b1, f1, n);
    k_gather2<<<(n + 3) / 4, 256, 0, stream>>>(off, src_sorted, dinv, f1, acc2, n);
    k_mm2_pool<<<(n + TILE_N - 1) / TILE_N, GEMM_TPB, 0, stream>>>(acc2, W2, b2, batch, out, n);
    k_div<<<(out_size + TPB - 1) / TPB, TPB, 0, stream>>>(out, cnt, out_size);
}